// Round 18
// baseline (42.529 us; speedup 1.0000x reference)
//
#include <hip/hip_runtime.h>

#define DISP_W 1.0f
#define MAT_W  0.1f
#define CD_W   0.5f

typedef _Float16 half8 __attribute__((ext_vector_type(8)));
typedef float f32x16 __attribute__((ext_vector_type(16)));
typedef float f32x4  __attribute__((ext_vector_type(4)));

constexpr int BB = 4;           // batch
constexpr int NN = 8192;        // points per cloud
constexpr int THREADS = 256;    // 4 waves
constexpr int IB = 256;         // A-rows per block = 4 waves x 64 (2 frags/wave)
constexpr int JR = 512;         // B-cols per LDS stage (8KB hi + 8KB lo)
constexpr int NSTAGE = 4;       // pipelined stages per block (2048 cols)
constexpr int NIB = NN / IB;    // 32
constexpr int NJQ = NN / (JR * NSTAGE);    // 4 column quarters
constexpr int NCHUNK = JR / 32; // 16
constexpr int NPTS = 2 * BB * NN;          // 65536
constexpr int GRID = 2 * BB * NIB * NJQ;   // 1024 = exactly 4 blocks/CU
constexpr int RSTRIDE = 36;     // epilogue scratch row stride in floats (144 B)
constexpr int NBF = NPTS / 256; // build_frags blocks = 256

#if defined(__has_builtin)
#if __has_builtin(__builtin_amdgcn_global_load_lds)
#define HAVE_GLL 1
#endif
#endif

#ifdef HAVE_GLL
typedef __attribute__((address_space(3))) void lds_vp;
typedef const __attribute__((address_space(1))) void gbl_vp;
#define GLOAD_LDS(g, l) __builtin_amdgcn_global_load_lds((gbl_vp*)(g), (lds_vp*)(l), 16, 0, 0)
#endif

// Verified K=16 MFMA layout (rounds 3-17, absmax 0.0):
//  A: [xh yh zh  xh yh zh  xl yl | zl ch cl 1 1 0 0 0]
//  B: [uxh uyh uzh uxl uyl uzl uxh uyh | uzh 1 1 ch cl 0 0 0]  (u = -2*pos)
// dot = -2 a.b (hi/lo compensated) + ca + cb = |a-b|^2 (~f32 precision).

__global__ __launch_bounds__(256)
void build_frags(const float* __restrict__ pred_disp,
                 const float* __restrict__ target_disp,
                 const float* __restrict__ tmpl,
                 half8* __restrict__ fragA,      // [cloud][b][n][2] (hi,lo)
                 half8* __restrict__ fragBhi,    // [cloud][b][n]
                 half8* __restrict__ fragBlo,
                 float* __restrict__ dsum_ws,    // [NBF] per-block |d| partials
                 float* __restrict__ out)
{
    int p = blockIdx.x * 256 + threadIdx.x;     // 0..65535
    if (p == 0) out[0] = 0.0f;                  // deterministic re-zero each call
    int c = p >> 15;
    int b = (p >> 13) & (BB - 1);
    int n = p & (NN - 1);

    const float* dp = (c ? target_disp : pred_disp) + (size_t)b * NN * 3;
    const float* tp = tmpl + (size_t)b * NN * 3;

    int n3 = n * 3;
    float dx = dp[n3 + 0], dy = dp[n3 + 1], dz = dp[n3 + 2];
    float x = tp[n3 + 0] + dx;
    float y = tp[n3 + 1] + dy;
    float z = tp[n3 + 2] + dz;
    float cc = fmaf(x, x, fmaf(y, y, z * z));

    // fused disp L1 partial (c==0 threads only; avoids double count)
    float s = 0.0f;
    if (c == 0) {
        const float* td = target_disp + (size_t)b * NN * 3;
        s = fabsf(dx - td[n3 + 0]) + fabsf(dy - td[n3 + 1]) + fabsf(dz - td[n3 + 2]);
    }

    _Float16 xh = (_Float16)x;  _Float16 xl = (_Float16)(x - (float)xh);
    _Float16 yh = (_Float16)y;  _Float16 yl = (_Float16)(y - (float)yh);
    _Float16 zh = (_Float16)z;  _Float16 zl = (_Float16)(z - (float)zh);
    _Float16 ch = (_Float16)cc; _Float16 cl = (_Float16)(cc - (float)ch);

    float ux = -2.0f * x, uy = -2.0f * y, uz = -2.0f * z;
    _Float16 uxh = (_Float16)ux; _Float16 uxl = (_Float16)(ux - (float)uxh);
    _Float16 uyh = (_Float16)uy; _Float16 uyl = (_Float16)(uy - (float)uyh);
    _Float16 uzh = (_Float16)uz; _Float16 uzl = (_Float16)(uz - (float)uzh);

    const _Float16 one  = (_Float16)1.0f;
    const _Float16 zero = (_Float16)0.0f;

    half8 aHi = {xh, yh, zh, xh, yh, zh, xl, yl};
    half8 aLo = {zl, ch, cl, one, one, zero, zero, zero};
    half8 bHi = {uxh, uyh, uzh, uxl, uyl, uzl, uxh, uyh};
    half8 bLo = {uzh, one, one, ch, cl, zero, zero, zero};

    fragA[(size_t)p * 2 + 0] = aHi;
    fragA[(size_t)p * 2 + 1] = aLo;
    fragBhi[p] = bHi;
    fragBlo[p] = bLo;

    // block-reduce s -> dsum_ws[blockIdx] (indexed write, no atomics/zeroing)
    for (int off = 32; off > 0; off >>= 1)
        s += __shfl_down(s, off, 64);
    __shared__ float ws4[4];
    int lane = threadIdx.x & 63, w = threadIdx.x >> 6;
    if (lane == 0) ws4[w] = s;
    __syncthreads();
    if (threadIdx.x == 0)
        dsum_ws[blockIdx.x] = ws4[0] + ws4[1] + ws4[2] + ws4[3];
}

__global__ __launch_bounds__(THREADS, 4)   // ~100 unified regs -> 4 waves/SIMD
void chamfer_mfma(const half8* __restrict__ fragA,
                  const half8* __restrict__ fragBhi,
                  const half8* __restrict__ fragBlo,
                  float* __restrict__ rowpart)
{
    // 32 KB LDS: double-buffered hi/lo staging; reused as transpose scratch
    __shared__ __align__(16) char lds_raw[32768];
    half8* bHi0 = (half8*)lds_raw;             // 8 KB
    half8* bLo0 = (half8*)(lds_raw + 8192);    // 8 KB
    half8* bHi1 = (half8*)(lds_raw + 16384);   // 8 KB
    half8* bLo1 = (half8*)(lds_raw + 24576);   // 8 KB

    int bx = blockIdx.x;
    int jq   = bx & (NJQ - 1);
    int iBlk = (bx >> 2) & (NIB - 1);
    int b    = (bx >> 7) & (BB - 1);
    int dir  = bx >> 9;
    int cA = dir, cB = dir ^ 1;

    const int tid  = threadIdx.x;
    const int lane = tid & 63;
    const int w    = tid >> 6;
    const int hi   = lane >> 5;
    const int li   = lane & 31;

    // ---- two A fragments per wave (rows i0, i0+32), loaded once ----
    int i0 = iBlk * IB + w * 64 + li;
    size_t aBase = ((size_t)cA * BB + b) * NN;
    half8 aF0 = fragA[(aBase + i0) * 2 + hi];
    half8 aF1 = fragA[(aBase + i0 + 32) * 2 + hi];

    size_t pB = ((size_t)cB * BB + b) * NN + (size_t)jq * (JR * NSTAGE);
    const half8* gHi = fragBhi + pB;
    const half8* gLo = fragBlo + pB;

    const int wb64 = w * 64;
    f32x16 kZero = {0.f,0.f,0.f,0.f, 0.f,0.f,0.f,0.f, 0.f,0.f,0.f,0.f, 0.f,0.f,0.f,0.f};
    float rm0[16], rm1[16];
    #pragma unroll
    for (int r = 0; r < 16; ++r) { rm0[r] = 1.0e30f; rm1[r] = 1.0e30f; }

#ifdef HAVE_GLL
    // async stage issue: dest = uniform (t,w) base + lane*16 (linear layout ok)
    #define ISSUE_STAGE(dHi, dLo, s_)                                          \
        { const half8* srcHi = gHi + (size_t)(s_) * JR;                        \
          const half8* srcLo = gLo + (size_t)(s_) * JR;                        \
          _Pragma("unroll")                                                    \
          for (int t = 0; t < JR / THREADS; ++t) {                             \
              int base = t * THREADS + wb64;                                   \
              GLOAD_LDS(srcHi + base + lane, (dHi) + base);                    \
              GLOAD_LDS(srcLo + base + lane, (dLo) + base);                    \
          } }
#else
    #define ISSUE_STAGE(dHi, dLo, s_)                                          \
        { const half8* srcHi = gHi + (size_t)(s_) * JR;                        \
          const half8* srcLo = gLo + (size_t)(s_) * JR;                        \
          _Pragma("unroll")                                                    \
          for (int t = 0; t < JR / THREADS; ++t) {                             \
              int idx = t * THREADS + tid;                                     \
              (dHi)[idx] = srcHi[idx];                                         \
              (dLo)[idx] = srcLo[idx];                                         \
          } }
#endif

    ISSUE_STAGE(bHi0, bLo0, 0);
    __syncthreads();   // drains async loads (compiler emits vmcnt(0) before barrier)

    #pragma unroll
    for (int s = 0; s < NSTAGE; ++s) {
        half8* curHi = (s & 1) ? bHi1 : bHi0;
        half8* curLo = (s & 1) ? bLo1 : bLo0;
        if (s + 1 < NSTAGE)   // issue next stage into the other buffer (async)
            ISSUE_STAGE((s & 1) ? bHi0 : bHi1, (s & 1) ? bLo0 : bLo1, s + 1);

        const half8* baseB = hi ? curLo : curHi;
        // 1 ds_read feeds 2 MFMAs; dual plain-fmin chains (VGPR/AGPR-direct)
        #pragma unroll 4
        for (int c = 0; c < NCHUNK; ++c) {
            half8 b0 = baseB[c * 32 + li];
            f32x16 a0 = __builtin_amdgcn_mfma_f32_32x32x16_f16(aF0, b0, kZero, 0, 0, 0);
            f32x16 a1 = __builtin_amdgcn_mfma_f32_32x32x16_f16(aF1, b0, kZero, 0, 0, 0);
            #pragma unroll
            for (int r = 0; r < 16; ++r)
                rm0[r] = fminf(rm0[r], a0[r]);
            #pragma unroll
            for (int r = 0; r < 16; ++r)
                rm1[r] = fminf(rm1[r], a1[r]);
        }
        __syncthreads();   // next-stage loads landed; cur buffer free to overwrite
    }

    // ---- epilogue: two per-wave LDS-transpose passes, coalesced stores ----
    float* scr = (float*)lds_raw;
    int wbase = w * (32 * RSTRIDE);                 // per-wave 4608 B region
    int cbase = wbase + hi * 4 * RSTRIDE + li;
    size_t obase = ((size_t)(dir * BB + b) * NJQ + jq) * NN
                 + (size_t)iBlk * IB + w * 64;

    // pass 0: rows i0 block
    #pragma unroll
    for (int r = 0; r < 16; ++r)
        scr[cbase + ((r & 3) + 8 * (r >> 2)) * RSTRIDE] = rm0[r];
    __syncthreads();
    {
        const f32x4* rp = (const f32x4*)&scr[wbase + (lane & 31) * RSTRIDE];
        f32x4 q0 = rp[0], q1 = rp[1], q2 = rp[2], q3 = rp[3];
        f32x4 q4 = rp[4], q5 = rp[5], q6 = rp[6], q7 = rp[7];
        f32x4 m4;
        #pragma unroll
        for (int k = 0; k < 4; ++k)
            m4[k] = fminf(fminf(fminf(q0[k], q1[k]), fminf(q2[k], q3[k])),
                          fminf(fminf(q4[k], q5[k]), fminf(q6[k], q7[k])));
        float m = fminf(fminf(m4[0], m4[1]), fminf(m4[2], m4[3]));
        if (lane < 32) rowpart[obase + lane] = m;
    }
    __syncthreads();

    // pass 1: rows i0+32 block
    #pragma unroll
    for (int r = 0; r < 16; ++r)
        scr[cbase + ((r & 3) + 8 * (r >> 2)) * RSTRIDE] = rm1[r];
    __syncthreads();
    {
        const f32x4* rp = (const f32x4*)&scr[wbase + (lane & 31) * RSTRIDE];
        f32x4 q0 = rp[0], q1 = rp[1], q2 = rp[2], q3 = rp[3];
        f32x4 q4 = rp[4], q5 = rp[5], q6 = rp[6], q7 = rp[7];
        f32x4 m4;
        #pragma unroll
        for (int k = 0; k < 4; ++k)
            m4[k] = fminf(fminf(fminf(q0[k], q1[k]), fminf(q2[k], q3[k])),
                          fminf(fminf(q4[k], q5[k]), fminf(q6[k], q7[k])));
        float m = fminf(fminf(m4[0], m4[1]), fminf(m4[2], m4[3]));
        if (lane < 32) rowpart[obase + 32 + lane] = m;
    }
}

__global__ __launch_bounds__(256)
void final_reduce(const float* __restrict__ pred_mat,
                  const float* __restrict__ target_mat,
                  const float* __restrict__ rowpart,
                  const float* __restrict__ dsum_ws,
                  float* __restrict__ out)
{
    const int NROWS = 2 * BB * NN;   // 65536

    int gtid = blockIdx.x * blockDim.x + threadIdx.x;
    int gstride = gridDim.x * blockDim.x;

    float msum = 0.0f;
    for (int t = gtid; t < NROWS; t += gstride) {
        int db = t >> 13;            // dir*BB + b
        int i  = t & (NN - 1);
        const float* p = rowpart + (size_t)db * NJQ * NN + i;
        float m = fminf(fminf(p[0], p[(size_t)NN]),
                        fminf(p[(size_t)2 * NN], p[(size_t)3 * NN]));
        msum += fmaxf(m, 0.0f);      // clamp tiny negatives from dot-form
    }

    float acc = msum * (CD_W / (float)(BB * NN));

    if (gtid < NBF)
        acc += dsum_ws[gtid] * (DISP_W / (float)(BB * NN * 3));

    if (gtid < 2 * BB) {
        float d = pred_mat[gtid] - target_mat[gtid];
        acc += d * d * (MAT_W / (float)(2 * BB));
    }

    for (int off = 32; off > 0; off >>= 1)
        acc += __shfl_down(acc, off, 64);

    __shared__ float wsum[4];
    if ((threadIdx.x & 63) == 0) wsum[threadIdx.x >> 6] = acc;
    __syncthreads();
    if (threadIdx.x == 0)
        atomicAdd(out, wsum[0] + wsum[1] + wsum[2] + wsum[3]);
}

extern "C" void kernel_launch(void* const* d_in, const int* in_sizes, int n_in,
                              void* d_out, int out_size, void* d_ws, size_t ws_size,
                              hipStream_t stream) {
    const float* pred_disp   = (const float*)d_in[0];
    const float* pred_mat    = (const float*)d_in[1];
    const float* target_disp = (const float*)d_in[2];
    const float* target_mat  = (const float*)d_in[3];
    const float* tmpl        = (const float*)d_in[4];

    // ws layout:
    //   fragA   : NPTS*2 half8 = 2 MB
    //   fragBhi : NPTS   half8 = 1 MB
    //   fragBlo : NPTS   half8 = 1 MB
    //   rowpart : 2*BB*NJQ*NN floats = 1 MB (every slot written exactly once)
    //   dsum_ws : NBF floats               (every slot written exactly once)
    half8* fragA   = (half8*)d_ws;
    half8* fragBhi = fragA + (size_t)NPTS * 2;
    half8* fragBlo = fragBhi + NPTS;
    float* rowpart = (float*)(fragBlo + NPTS);
    float* dsum_ws = rowpart + (size_t)2 * BB * NJQ * NN;
    float* out = (float*)d_out;

    build_frags<<<NBF, 256, 0, stream>>>(pred_disp, target_disp, tmpl,
                                         fragA, fragBhi, fragBlo, dsum_ws, out);
    chamfer_mfma<<<GRID, THREADS, 0, stream>>>(fragA, fragBhi, fragBlo, rowpart);
    final_reduce<<<128, 256, 0, stream>>>(pred_mat, target_mat, rowpart, dsum_ws, out);
}

// Round 19
// 33.116 us; speedup vs baseline: 1.2842x; 1.2842x over previous
//
#include <hip/hip_runtime.h>

#define DISP_W 1.0f
#define MAT_W  0.1f
#define CD_W   0.5f

typedef _Float16 half8 __attribute__((ext_vector_type(8)));
typedef float f32x16 __attribute__((ext_vector_type(16)));
typedef float f32x4  __attribute__((ext_vector_type(4)));

constexpr int BB = 4;           // batch
constexpr int NN = 8192;        // points per cloud
constexpr int THREADS = 256;    // 4 waves
constexpr int IB = 256;         // A-rows per block = 4 waves x 64 (2 frags/wave)
constexpr int JR = 1024;        // B-cols per LDS stage
constexpr int NSTAGE = 2;       // pipelined stages per block (2048 cols)
constexpr int NIB = NN / IB;    // 32
constexpr int NJQ = NN / (JR * NSTAGE);    // 4 column quarters
constexpr int NCHUNK = JR / 32; // 32
constexpr int NPTS = 2 * BB * NN;          // 65536
constexpr int GRID = 2 * BB * NIB * NJQ;   // 1024 = 4 blocks/CU supply
constexpr int RSTRIDE = 36;     // epilogue scratch row stride in floats (144 B)
constexpr int NBF = NPTS / 256; // build_frags blocks = 256
constexpr int PFT = JR / THREADS;          // 4 prefetch half8 per array per thread

// Verified K=16 MFMA layout (rounds 3-18, absmax 0.0):
//  A: [xh yh zh  xh yh zh  xl yl | zl ch cl 1 1 0 0 0]
//  B: [uxh uyh uzh uxl uyl uzl uxh uyh | uzh 1 1 ch cl 0 0 0]  (u = -2*pos)
// dot = -2 a.b (hi/lo compensated) + ca + cb = |a-b|^2 (~f32 precision).

__global__ __launch_bounds__(256)
void build_frags(const float* __restrict__ pred_disp,
                 const float* __restrict__ target_disp,
                 const float* __restrict__ tmpl,
                 half8* __restrict__ fragA,      // [cloud][b][n][2] (hi,lo)
                 half8* __restrict__ fragBhi,    // [cloud][b][n]
                 half8* __restrict__ fragBlo,
                 float* __restrict__ dsum_ws,    // [NBF] per-block |d| partials
                 float* __restrict__ out)
{
    int p = blockIdx.x * 256 + threadIdx.x;     // 0..65535
    if (p == 0) out[0] = 0.0f;                  // deterministic re-zero each call
    int c = p >> 15;
    int b = (p >> 13) & (BB - 1);
    int n = p & (NN - 1);

    const float* dp = (c ? target_disp : pred_disp) + (size_t)b * NN * 3;
    const float* tp = tmpl + (size_t)b * NN * 3;

    int n3 = n * 3;
    float dx = dp[n3 + 0], dy = dp[n3 + 1], dz = dp[n3 + 2];
    float x = tp[n3 + 0] + dx;
    float y = tp[n3 + 1] + dy;
    float z = tp[n3 + 2] + dz;
    float cc = fmaf(x, x, fmaf(y, y, z * z));

    // fused disp L1 partial (c==0 threads only; avoids double count)
    float s = 0.0f;
    if (c == 0) {
        const float* td = target_disp + (size_t)b * NN * 3;
        s = fabsf(dx - td[n3 + 0]) + fabsf(dy - td[n3 + 1]) + fabsf(dz - td[n3 + 2]);
    }

    _Float16 xh = (_Float16)x;  _Float16 xl = (_Float16)(x - (float)xh);
    _Float16 yh = (_Float16)y;  _Float16 yl = (_Float16)(y - (float)yh);
    _Float16 zh = (_Float16)z;  _Float16 zl = (_Float16)(z - (float)zh);
    _Float16 ch = (_Float16)cc; _Float16 cl = (_Float16)(cc - (float)ch);

    float ux = -2.0f * x, uy = -2.0f * y, uz = -2.0f * z;
    _Float16 uxh = (_Float16)ux; _Float16 uxl = (_Float16)(ux - (float)uxh);
    _Float16 uyh = (_Float16)uy; _Float16 uyl = (_Float16)(uy - (float)uyh);
    _Float16 uzh = (_Float16)uz; _Float16 uzl = (_Float16)(uz - (float)uzh);

    const _Float16 one  = (_Float16)1.0f;
    const _Float16 zero = (_Float16)0.0f;

    half8 aHi = {xh, yh, zh, xh, yh, zh, xl, yl};
    half8 aLo = {zl, ch, cl, one, one, zero, zero, zero};
    half8 bHi = {uxh, uyh, uzh, uxl, uyl, uzl, uxh, uyh};
    half8 bLo = {uzh, one, one, ch, cl, zero, zero, zero};

    fragA[(size_t)p * 2 + 0] = aHi;
    fragA[(size_t)p * 2 + 1] = aLo;
    fragBhi[p] = bHi;
    fragBlo[p] = bLo;

    // block-reduce s -> dsum_ws[blockIdx] (indexed write, no atomics/zeroing)
    for (int off = 32; off > 0; off >>= 1)
        s += __shfl_down(s, off, 64);
    __shared__ float ws4[4];
    int lane = threadIdx.x & 63, w = threadIdx.x >> 6;
    if (lane == 0) ws4[w] = s;
    __syncthreads();
    if (threadIdx.x == 0)
        dsum_ws[blockIdx.x] = ws4[0] + ws4[1] + ws4[2] + ws4[3];
}

__global__ __launch_bounds__(THREADS, 2)   // 256-reg budget: accs + prefetch in VGPRs
void chamfer_mfma(const half8* __restrict__ fragA,
                  const half8* __restrict__ fragBhi,
                  const half8* __restrict__ fragBlo,
                  float* __restrict__ rowpart)
{
    // 32 KB LDS: single staging buffer (reg-prefetch pipeline), reused as scratch
    __shared__ __align__(16) char lds_raw[32768];
    half8* sBhi = (half8*)lds_raw;            // 16 KB
    half8* sBlo = (half8*)(lds_raw + 16384);  // 16 KB

    int bx = blockIdx.x;
    int jq   = bx & (NJQ - 1);
    int iBlk = (bx >> 2) & (NIB - 1);
    int b    = (bx >> 7) & (BB - 1);
    int dir  = bx >> 9;
    int cA = dir, cB = dir ^ 1;

    const int tid  = threadIdx.x;
    const int lane = tid & 63;
    const int w    = tid >> 6;
    const int hi   = lane >> 5;
    const int li   = lane & 31;

    // ---- two A fragments per wave (rows i0, i0+32), loaded once ----
    int i0 = iBlk * IB + w * 64 + li;
    size_t aBase = ((size_t)cA * BB + b) * NN;
    half8 aF0 = fragA[(aBase + i0) * 2 + hi];
    half8 aF1 = fragA[(aBase + i0 + 32) * 2 + hi];

    size_t pB = ((size_t)cB * BB + b) * NN + (size_t)jq * (JR * NSTAGE);
    const half8* gHi = fragBhi + pB;
    const half8* gLo = fragBlo + pB;

    f32x16 kZero = {0.f,0.f,0.f,0.f, 0.f,0.f,0.f,0.f, 0.f,0.f,0.f,0.f, 0.f,0.f,0.f,0.f};
    float rm0[16], rm1[16];
    #pragma unroll
    for (int r = 0; r < 16; ++r) { rm0[r] = 1.0e30f; rm1[r] = 1.0e30f; }

    // ---- T14 pipeline: prefetch stage s+1 to regs during stage-s compute ----
    half8 pfHi[PFT], pfLo[PFT];
    // prologue: stage 0
    #pragma unroll
    for (int t = 0; t < PFT; ++t) {
        pfHi[t] = gHi[t * THREADS + tid];
        pfLo[t] = gLo[t * THREADS + tid];
    }
    #pragma unroll
    for (int t = 0; t < PFT; ++t) {
        sBhi[t * THREADS + tid] = pfHi[t];
        sBlo[t * THREADS + tid] = pfLo[t];
    }
    __syncthreads();

    for (int s = 0; s < NSTAGE; ++s) {
        // issue next stage's global loads (results unused until after barrier)
        if (s + 1 < NSTAGE) {
            const half8* srcHi = gHi + (size_t)(s + 1) * JR;
            const half8* srcLo = gLo + (size_t)(s + 1) * JR;
            #pragma unroll
            for (int t = 0; t < PFT; ++t) {
                pfHi[t] = srcHi[t * THREADS + tid];
                pfLo[t] = srcLo[t * THREADS + tid];
            }
        }

        const half8* baseB = hi ? sBlo : sBhi;
        // 1 ds_read feeds 2 MFMAs; dual plain-fmin chains (VGPR-form winner)
        #pragma unroll 4
        for (int c = 0; c < NCHUNK; ++c) {
            half8 b0 = baseB[c * 32 + li];
            f32x16 a0 = __builtin_amdgcn_mfma_f32_32x32x16_f16(aF0, b0, kZero, 0, 0, 0);
            f32x16 a1 = __builtin_amdgcn_mfma_f32_32x32x16_f16(aF1, b0, kZero, 0, 0, 0);
            #pragma unroll
            for (int r = 0; r < 16; ++r)
                rm0[r] = fminf(rm0[r], a0[r]);
            #pragma unroll
            for (int r = 0; r < 16; ++r)
                rm1[r] = fminf(rm1[r], a1[r]);
        }
        __syncthreads();   // all waves done reading before overwrite

        if (s + 1 < NSTAGE) {
            #pragma unroll
            for (int t = 0; t < PFT; ++t) {
                sBhi[t * THREADS + tid] = pfHi[t];
                sBlo[t * THREADS + tid] = pfLo[t];
            }
            __syncthreads();
        }
    }

    // ---- epilogue: two per-wave LDS-transpose passes, coalesced stores ----
    float* scr = (float*)lds_raw;
    int wbase = w * (32 * RSTRIDE);                 // per-wave 4608 B region
    int cbase = wbase + hi * 4 * RSTRIDE + li;
    size_t obase = ((size_t)(dir * BB + b) * NJQ + jq) * NN
                 + (size_t)iBlk * IB + w * 64;

    // pass 0: rows i0 block
    #pragma unroll
    for (int r = 0; r < 16; ++r)
        scr[cbase + ((r & 3) + 8 * (r >> 2)) * RSTRIDE] = rm0[r];
    __syncthreads();
    {
        const f32x4* rp = (const f32x4*)&scr[wbase + (lane & 31) * RSTRIDE];
        f32x4 q0 = rp[0], q1 = rp[1], q2 = rp[2], q3 = rp[3];
        f32x4 q4 = rp[4], q5 = rp[5], q6 = rp[6], q7 = rp[7];
        f32x4 m4;
        #pragma unroll
        for (int k = 0; k < 4; ++k)
            m4[k] = fminf(fminf(fminf(q0[k], q1[k]), fminf(q2[k], q3[k])),
                          fminf(fminf(q4[k], q5[k]), fminf(q6[k], q7[k])));
        float m = fminf(fminf(m4[0], m4[1]), fminf(m4[2], m4[3]));
        if (lane < 32) rowpart[obase + lane] = m;
    }
    __syncthreads();

    // pass 1: rows i0+32 block
    #pragma unroll
    for (int r = 0; r < 16; ++r)
        scr[cbase + ((r & 3) + 8 * (r >> 2)) * RSTRIDE] = rm1[r];
    __syncthreads();
    {
        const f32x4* rp = (const f32x4*)&scr[wbase + (lane & 31) * RSTRIDE];
        f32x4 q0 = rp[0], q1 = rp[1], q2 = rp[2], q3 = rp[3];
        f32x4 q4 = rp[4], q5 = rp[5], q6 = rp[6], q7 = rp[7];
        f32x4 m4;
        #pragma unroll
        for (int k = 0; k < 4; ++k)
            m4[k] = fminf(fminf(fminf(q0[k], q1[k]), fminf(q2[k], q3[k])),
                          fminf(fminf(q4[k], q5[k]), fminf(q6[k], q7[k])));
        float m = fminf(fminf(m4[0], m4[1]), fminf(m4[2], m4[3]));
        if (lane < 32) rowpart[obase + 32 + lane] = m;
    }
}

__global__ __launch_bounds__(256)
void final_reduce(const float* __restrict__ pred_mat,
                  const float* __restrict__ target_mat,
                  const float* __restrict__ rowpart,
                  const float* __restrict__ dsum_ws,
                  float* __restrict__ out)
{
    const int NROWS = 2 * BB * NN;   // 65536

    int gtid = blockIdx.x * blockDim.x + threadIdx.x;
    int gstride = gridDim.x * blockDim.x;

    float msum = 0.0f;
    for (int t = gtid; t < NROWS; t += gstride) {
        int db = t >> 13;            // dir*BB + b
        int i  = t & (NN - 1);
        const float* p = rowpart + (size_t)db * NJQ * NN + i;
        float m = 1.0e30f;
        #pragma unroll
        for (int jb = 0; jb < NJQ; ++jb)
            m = fminf(m, p[(size_t)jb * NN]);
        msum += fmaxf(m, 0.0f);      // clamp tiny negatives from dot-form
    }

    float acc = msum * (CD_W / (float)(BB * NN));

    if (gtid < NBF)
        acc += dsum_ws[gtid] * (DISP_W / (float)(BB * NN * 3));

    if (gtid < 2 * BB) {
        float d = pred_mat[gtid] - target_mat[gtid];
        acc += d * d * (MAT_W / (float)(2 * BB));
    }

    for (int off = 32; off > 0; off >>= 1)
        acc += __shfl_down(acc, off, 64);

    __shared__ float wsum[4];
    if ((threadIdx.x & 63) == 0) wsum[threadIdx.x >> 6] = acc;
    __syncthreads();
    if (threadIdx.x == 0)
        atomicAdd(out, wsum[0] + wsum[1] + wsum[2] + wsum[3]);
}

extern "C" void kernel_launch(void* const* d_in, const int* in_sizes, int n_in,
                              void* d_out, int out_size, void* d_ws, size_t ws_size,
                              hipStream_t stream) {
    const float* pred_disp   = (const float*)d_in[0];
    const float* pred_mat    = (const float*)d_in[1];
    const float* target_disp = (const float*)d_in[2];
    const float* target_mat  = (const float*)d_in[3];
    const float* tmpl        = (const float*)d_in[4];

    // ws layout:
    //   fragA   : NPTS*2 half8 = 2 MB
    //   fragBhi : NPTS   half8 = 1 MB
    //   fragBlo : NPTS   half8 = 1 MB
    //   rowpart : 2*BB*NJQ*NN floats = 1 MB (every slot written exactly once)
    //   dsum_ws : NBF floats               (every slot written exactly once)
    half8* fragA   = (half8*)d_ws;
    half8* fragBhi = fragA + (size_t)NPTS * 2;
    half8* fragBlo = fragBhi + NPTS;
    float* rowpart = (float*)(fragBlo + NPTS);
    float* dsum_ws = rowpart + (size_t)2 * BB * NJQ * NN;
    float* out = (float*)d_out;

    build_frags<<<NBF, 256, 0, stream>>>(pred_disp, target_disp, tmpl,
                                         fragA, fragBhi, fragBlo, dsum_ws, out);
    chamfer_mfma<<<GRID, THREADS, 0, stream>>>(fragA, fragBhi, fragBlo, rowpart);
    final_reduce<<<128, 256, 0, stream>>>(pred_mat, target_mat, rowpart, dsum_ws, out);
}